// Round 12
// baseline (642.724 us; speedup 1.0000x reference)
//
#include <hip/hip_runtime.h>
#include <math.h>

// Problem constants
#define B_  32
#define L_  1024
#define T_  (B_ * L_)       // 32768 tokens
#define DM_ 128
#define DI_ 256
#define DS_ 16
#define DC_ 4
#define DR_ 8
#define NC_ 10
#define CHUNK_ 64
#define NCH_  (L_ / CHUNK_)   // 16 chunks
#define PSTR_ 288             // projall row stride (bf16): 256 delta | 32 B,C

typedef __bf16 bf16x8 __attribute__((ext_vector_type(8)));
typedef __bf16 bf16x4 __attribute__((ext_vector_type(4)));
typedef __bf16 bf16x2 __attribute__((ext_vector_type(2)));
typedef float f32x4 __attribute__((ext_vector_type(4)));
typedef unsigned short u16x8 __attribute__((ext_vector_type(8)));

__device__ __forceinline__ float sigmoidf_(float x) { return 1.0f / (1.0f + __expf(-x)); }
__device__ __forceinline__ float siluf_(float x)    { return x * sigmoidf_(x); }
__device__ __forceinline__ float softplusf_(float x) {
    return (x > 15.0f) ? x : __logf(1.0f + __expf(x));
}
__device__ __forceinline__ float fexp2_(float x) { return __builtin_amdgcn_exp2f(x); }

// async 16B global->LDS (gfx950). dest = wave-uniform base + lane*16.
__device__ __forceinline__ void gload_lds16(const __bf16* g, __bf16* l) {
    __builtin_amdgcn_global_load_lds(
        (const __attribute__((address_space(1))) void*)g,
        (__attribute__((address_space(3))) void*)l, 16, 0, 0);
}

// Stage an R x 64 bf16 tile (row stride `stride`, col offset k0) into LDS with
// XOR-swizzle baked in: LDS (row, sw) holds source (row, sw ^ (row&7)).
template<int R>
__device__ __forceinline__ void stage_async(const __bf16* __restrict__ src,
        __bf16* lds, int k0, int stride, int wid, int lane) {
    constexpr int NI = R / 32;
#pragma unroll
    for (int j = 0; j < NI; ++j) {
        int s0 = (wid * NI + j) * 64;
        int s = s0 + lane;
        int row = s >> 3, sw = s & 7;
        int slot = sw ^ (row & 7);
        gload_lds16(src + (size_t)row * stride + k0 + slot * 8, lds + (size_t)s0 * 8);
    }
}

// ---------------- embed -----------------------------------------------------------
__global__ __launch_bounds__(128) void k_embed(const float* __restrict__ x,
        const float* __restrict__ Win, const float* __restrict__ bin,
        float* __restrict__ h) {
    int t = blockIdx.x;
    int b = t >> 10, l = t & 1023;
    int m = threadIdx.x;
    const float* xb = x + (size_t)b * 3 * 1024 + l;
    float acc = bin[m];
    acc = fmaf(xb[0],    Win[m],        acc);
    acc = fmaf(xb[1024], Win[128 + m],  acc);
    acc = fmaf(xb[2048], Win[256 + m],  acc);
    h[(size_t)t * 128 + m] = acc;
}

// ---------------- merged weight prep ----------------------------------------------
// wt1[lay][n<512][k<128]; wt2[lay][n<128][k<256]; wcat[lay][n<384][k<256].
__global__ __launch_bounds__(256) void k_prep(const float* __restrict__ ipw,
        const float* __restrict__ opw, const float* __restrict__ xpw,
        const float* __restrict__ dtw, __bf16* __restrict__ wt1,
        __bf16* __restrict__ wt2, __bf16* __restrict__ wcat) {
    int blk = blockIdx.x;              // 0..1535
    int tid = threadIdx.x;
    int i = blk * 256 + tid;
    if (i < 262144) {
        int lay = i >> 16, rem = i & 65535, n = rem >> 7, k = rem & 127;
        wt1[i] = (__bf16)ipw[lay * 65536 + k * 512 + n];
    }
    if (i < 131072) {
        int lay = i >> 15, rem = i & 32767, n = rem >> 8, k = rem & 255;
        wt2[i] = (__bf16)opw[lay * 32768 + k * 128 + n];
    }
    {
        int lay = blk / 384, n = blk % 384;
        int k = tid;
        float v;
        if (n < 256) {
            float acc = 0.0f;
#pragma unroll
            for (int r = 0; r < 8; ++r)
                acc = fmaf(xpw[lay * 10240 + k * 40 + r], dtw[lay * 2048 + r * 256 + n], acc);
            v = acc;
        } else if (n < 288) {
            v = xpw[lay * 10240 + k * 40 + (n - 248)];   // col 8 + (n-256)
        } else {
            v = 0.0f;
        }
        wcat[(size_t)blk * 256 + k] = (__bf16)v;
    }
}

// ---------------- layernorm -> bf16 (layer 0 only) --------------------------------
__global__ __launch_bounds__(256) void k_ln(const float* __restrict__ h,
        const float* __restrict__ w, const float* __restrict__ b,
        __bf16* __restrict__ z) {
    int wid = threadIdx.x >> 6, lane = threadIdx.x & 63;
    int t = blockIdx.x * 4 + wid;
    const float* hr = h + (size_t)t * 128;
    float2 v = *(const float2*)(hr + lane * 2);
    float s = v.x + v.y, sq = v.x * v.x + v.y * v.y;
#pragma unroll
    for (int off = 1; off < 64; off <<= 1) {
        s += __shfl_xor(s, off);
        sq += __shfl_xor(sq, off);
    }
    float mean = s * (1.0f / 128.0f);
    float var = sq * (1.0f / 128.0f) - mean * mean;
    float rstd = rsqrtf(var + 1e-5f);
    float2 wv = *(const float2*)(w + lane * 2);
    float2 bv = *(const float2*)(b + lane * 2);
    bf16x2 o;
    o.x = (__bf16)((v.x - mean) * rstd * wv.x + bv.x);
    o.y = (__bf16)((v.y - mean) * rstd * wv.y + bv.y);
    *(bf16x2*)(z + (size_t)t * 128 + lane * 2) = o;
}

// ---------------- bf16 MFMA GEMM, BM x 128 tile, BK=64 ---------------------------
// MODE 0: store bf16 (stride N)              [gemm1 -> xzb]
// MODE 1: col<256 softplus+bias bf16, col<288 raw bf16; stride PSTR_  [xproj]
// MODE 2: Cf += acc + bias (f32, stride N)   [gemm2 -> h]
// GATE: A element = f32(A[m][k]) * silu(f32(G[m*512+256+k]))
// WLN (MODE 2 only, N=128, bn=0): fused row-LayerNorm of the final h rows,
// writing next layer's zb (bf16).
template<int BM, int K, int N, int MODE, bool GATE, bool WLN>
__global__ __launch_bounds__(256) void k_gemm_mfma(
        const __bf16* __restrict__ A, const __bf16* __restrict__ G,
        const __bf16* __restrict__ Wt, const float* __restrict__ bias,
        float* __restrict__ Cf, __bf16* __restrict__ Cb,
        const float* __restrict__ lnw, const float* __restrict__ lnb,
        __bf16* __restrict__ Zb) {
    static_assert(!GATE || BM == 32, "GATE staging assumes BM=32");
    static_assert(!WLN || (MODE == 2 && BM == 32 && N == 128), "WLN geometry");
    __shared__ __bf16 As[BM * 64];
    __shared__ __bf16 Bs[128 * 64];
    __shared__ float red_s[WLN ? 4 : 1][WLN ? 32 : 1];
    __shared__ float red_q[WLN ? 4 : 1][WLN ? 32 : 1];
    int tid = threadIdx.x;
    int bm = blockIdx.x, bn = blockIdx.y;
    int lane = tid & 63, wid = tid >> 6;
    int lr = lane & 15, lg = lane >> 4;
    constexpr int MF = BM / 16;

    f32x4 acc[MF][2] = {};
    const __bf16* Asrc = A + (size_t)(bm * BM) * K;
    const __bf16* Bsrc = Wt + (size_t)(bn * 128) * K;

    for (int k0 = 0; k0 < K; k0 += 64) {
        if (GATE) {
            int row = tid >> 3, slot = tid & 7;
            int m = bm * BM + row;
            bf16x8 yv = *(const bf16x8*)(A + (size_t)m * K + k0 + slot * 8);
            bf16x8 gv = *(const bf16x8*)(G + (size_t)m * 512 + 256 + k0 + slot * 8);
            bf16x8 v;
#pragma unroll
            for (int j = 0; j < 8; ++j)
                v[j] = (__bf16)((float)yv[j] * siluf_((float)gv[j]));
            *(bf16x8*)(As + row * 64 + ((slot ^ (row & 7)) * 8)) = v;
        } else {
            stage_async<BM>(Asrc, As, k0, K, wid, lane);
        }
        stage_async<128>(Bsrc, Bs, k0, K, wid, lane);
        __syncthreads();
#pragma unroll
        for (int ks = 0; ks < 2; ++ks) {
            int slotbase = ks * 4 + lg;
            bf16x8 af[MF], bfr[2];
#pragma unroll
            for (int m = 0; m < MF; ++m) {
                int row = m * 16 + lr;
                af[m] = *(const bf16x8*)(As + row * 64 + ((slotbase ^ (row & 7)) * 8));
            }
#pragma unroll
            for (int n = 0; n < 2; ++n) {
                int rn = wid * 32 + n * 16 + lr;
                bfr[n] = *(const bf16x8*)(Bs + rn * 64 + ((slotbase ^ (rn & 7)) * 8));
            }
#pragma unroll
            for (int m = 0; m < MF; ++m)
#pragma unroll
                for (int n = 0; n < 2; ++n)
                    acc[m][n] = __builtin_amdgcn_mfma_f32_16x16x32_bf16(
                        af[m], bfr[n], acc[m][n], 0, 0, 0);
        }
        __syncthreads();
    }
    // ---- epilogue: D[row=(lane>>4)*4+reg][col=lane&15] ----
    float vv[MF][2][4];
#pragma unroll
    for (int m = 0; m < MF; ++m) {
#pragma unroll
        for (int n = 0; n < 2; ++n) {
            int col = bn * 128 + wid * 32 + n * 16 + lr;
            float bv = (MODE == 2) ? bias[col] : 0.0f;
            float dtbv = (MODE == 1 && col < 256) ? bias[col] : 0.0f;
#pragma unroll
            for (int rg = 0; rg < 4; ++rg) {
                int row = bm * BM + m * 16 + lg * 4 + rg;
                float v = acc[m][n][rg];
                if (MODE == 0) {
                    Cb[(size_t)row * N + col] = (__bf16)v;
                } else if (MODE == 1) {
                    if (col < 256)
                        Cb[(size_t)row * PSTR_ + col] = (__bf16)softplusf_(v + dtbv);
                    else if (col < 288)
                        Cb[(size_t)row * PSTR_ + col] = (__bf16)v;
                } else {
                    float* cp = Cf + (size_t)row * N + col;
                    v += *cp + bv;
                    *cp = v;
                    vv[m][n][rg] = v;
                }
            }
        }
    }
    if (WLN) {
        // partial row sums over this thread's 2 cols, reduced over lr in-wave
        float ps[MF][4], pq[MF][4];
#pragma unroll
        for (int m = 0; m < MF; ++m)
#pragma unroll
            for (int rg = 0; rg < 4; ++rg) {
                float a = vv[m][0][rg], bv2 = vv[m][1][rg];
                ps[m][rg] = a + bv2;
                pq[m][rg] = a * a + bv2 * bv2;
            }
#pragma unroll
        for (int off = 1; off < 16; off <<= 1) {
#pragma unroll
            for (int m = 0; m < MF; ++m)
#pragma unroll
                for (int rg = 0; rg < 4; ++rg) {
                    ps[m][rg] += __shfl_xor(ps[m][rg], off);
                    pq[m][rg] += __shfl_xor(pq[m][rg], off);
                }
        }
        if (lr == 0) {
#pragma unroll
            for (int m = 0; m < MF; ++m)
#pragma unroll
                for (int rg = 0; rg < 4; ++rg) {
                    int rl = m * 16 + lg * 4 + rg;
                    red_s[wid][rl] = ps[m][rg];
                    red_q[wid][rl] = pq[m][rg];
                }
        }
        __syncthreads();
#pragma unroll
        for (int m = 0; m < MF; ++m)
#pragma unroll
            for (int rg = 0; rg < 4; ++rg) {
                int rl = m * 16 + lg * 4 + rg;
                float s = red_s[0][rl] + red_s[1][rl] + red_s[2][rl] + red_s[3][rl];
                float q = red_q[0][rl] + red_q[1][rl] + red_q[2][rl] + red_q[3][rl];
                float mean = s * (1.0f / 128.0f);
                float var = q * (1.0f / 128.0f) - mean * mean;
                float rstd = rsqrtf(var + 1e-5f);
#pragma unroll
                for (int n = 0; n < 2; ++n) {
                    int col = wid * 32 + n * 16 + lr;
                    float z = (vv[m][n][rg] - mean) * rstd * lnw[col] + lnb[col];
                    Zb[(size_t)(bm * BM + rl) * 128 + col] = (__bf16)z;
                }
            }
    }
}

// ---------------- causal depthwise conv (width 4) + SiLU, vectorized -------------
__global__ __launch_bounds__(256) void k_conv(const __bf16* __restrict__ xzb,
        const float* __restrict__ cw, const float* __restrict__ cb,
        __bf16* __restrict__ xcb) {
    int t = blockIdx.x * 4 + (threadIdx.x >> 6);
    int d0 = (threadIdx.x & 63) * 4;
    int l = t & 1023;
    const __bf16* xp = xzb + (size_t)t * 512 + d0;
    float4 wv[4];
#pragma unroll
    for (int j = 0; j < 4; ++j) wv[j] = *(const float4*)(cw + (d0 + j) * 4);
    float acc[4] = {cb[d0], cb[d0 + 1], cb[d0 + 2], cb[d0 + 3]};
#pragma unroll
    for (int k = 0; k < 4; ++k) {
        int back = 3 - k;
        if (l >= back) {
            bf16x4 v = *(const bf16x4*)(xp - back * 512);
#pragma unroll
            for (int j = 0; j < 4; ++j)
                acc[j] = fmaf((float)v[j], ((const float*)&wv[j])[k], acc[j]);
        }
    }
    bf16x4 o;
#pragma unroll
    for (int j = 0; j < 4; ++j) o[j] = (__bf16)siluf_(acc[j]);
    *(bf16x4*)(xcb + (size_t)t * 256 + d0) = o;
}

// ---------------- chunk-parallel SSM scan: one thread per d ----------------------
// Phase A (FINAL=false): local scan from 0 -> emit P (decay), S (local final).
// Phase C (FINAL=true): reconstructs H_c from P/S inline (combine fused), then
// scans and writes y. Block 128 threads (d = dg*128+tid), grid (2, NCH_, B_).
template<bool FINAL>
__global__ __launch_bounds__(128) void k_scan_chunk(
        const __bf16* __restrict__ projall, const __bf16* __restrict__ xcb,
        const float* __restrict__ Alog, const float* __restrict__ Dp,
        float* __restrict__ P, float* __restrict__ S,
        __bf16* __restrict__ yb) {
    __shared__ unsigned du_lds[CHUNK_ * 128];   // 32 KB
    __shared__ float bc[CHUNK_ * 32];           // 8 KB
    int b = blockIdx.z, c = blockIdx.y, dg = blockIdx.x;   // dg in {0,1}
    int tid = threadIdx.x;                      // 0..127
    int d = dg * 128 + tid;

    const __bf16* projC = projall + ((size_t)b * 1024 + c * CHUNK_) * PSTR_;
    const __bf16* xcC   = xcb + ((size_t)b * 1024 + c * CHUNK_) * 256 + dg * 128;

    // ---- stage delta|u interleaved ----
#pragma unroll
    for (int r = 0; r < 8; ++r) {
        int item = r * 128 + tid;               // 0..1023
        int t = item >> 4, o8 = (item & 15) * 8;
        u16x8 dv = *(const u16x8*)(projC + (size_t)t * PSTR_ + dg * 128 + o8);
        u16x8 xv = *(const u16x8*)(xcC + (size_t)t * 256 + o8);
        uint4 w0, w1;
        w0.x = dv[0] | ((unsigned)xv[0] << 16); w0.y = dv[1] | ((unsigned)xv[1] << 16);
        w0.z = dv[2] | ((unsigned)xv[2] << 16); w0.w = dv[3] | ((unsigned)xv[3] << 16);
        w1.x = dv[4] | ((unsigned)xv[4] << 16); w1.y = dv[5] | ((unsigned)xv[5] << 16);
        w1.z = dv[6] | ((unsigned)xv[6] << 16); w1.w = dv[7] | ((unsigned)xv[7] << 16);
        *(uint4*)(du_lds + t * 128 + o8)     = w0;
        *(uint4*)(du_lds + t * 128 + o8 + 4) = w1;
    }
    // ---- stage B|C as f32 ----
#pragma unroll
    for (int r = 0; r < 2; ++r) {
        int item = r * 128 + tid;               // 0..255
        int t = item >> 2, g8 = (item & 3) * 8;
        bf16x8 v = *(const bf16x8*)(projC + (size_t)t * PSTR_ + 256 + g8);
        float4 f0 = {(float)v[0], (float)v[1], (float)v[2], (float)v[3]};
        float4 f1 = {(float)v[4], (float)v[5], (float)v[6], (float)v[7]};
        *(float4*)(bc + t * 32 + g8)     = f0;
        *(float4*)(bc + t * 32 + g8 + 4) = f1;
    }

    // ---- per-thread constants: all 16 states ----
    float aa[16], hs[16];
#pragma unroll
    for (int jj = 0; jj < 4; ++jj) {
        float4 av = *(const float4*)(Alog + (size_t)d * 16 + jj * 4);
        aa[jj * 4 + 0] = -__expf(av.x) * 1.44269504088896f;
        aa[jj * 4 + 1] = -__expf(av.y) * 1.44269504088896f;
        aa[jj * 4 + 2] = -__expf(av.z) * 1.44269504088896f;
        aa[jj * 4 + 3] = -__expf(av.w) * 1.44269504088896f;
    }
    float Dpd = Dp[d];
    size_t psIdx = ((size_t)(b * NCH_ + c)) * 4096 + (size_t)d * 16;
#pragma unroll
    for (int j = 0; j < 16; ++j) hs[j] = 0.0f;
    if (FINAL) {
        // inline combine: H_c = fold of (P,S) over chunks 0..c-1
        for (int cc = 0; cc < c; ++cc) {
            size_t base = ((size_t)(b * NCH_ + cc)) * 4096 + (size_t)d * 16;
#pragma unroll
            for (int jj = 0; jj < 4; ++jj) {
                float4 p = *(const float4*)(P + base + jj * 4);
                float4 s = *(const float4*)(S + base + jj * 4);
                hs[jj * 4 + 0] = fmaf(p.x, hs[jj * 4 + 0], s.x);
                hs[jj * 4 + 1] = fmaf(p.y, hs[jj * 4 + 1], s.y);
                hs[jj * 4 + 2] = fmaf(p.z, hs[jj * 4 + 2], s.z);
                hs[jj * 4 + 3] = fmaf(p.w, hs[jj * 4 + 3], s.w);
            }
        }
    }
    float cumd = 0.0f;
    __bf16* yC = yb + ((size_t)b * 1024 + c * CHUNK_) * 256 + dg * 128 + tid;

    __syncthreads();
#pragma unroll 2
    for (int tt = 0; tt < CHUNK_; ++tt) {
        unsigned duv = du_lds[tt * 128 + tid];
        float delta_t = __uint_as_float(duv << 16);
        float u = __uint_as_float(duv & 0xffff0000u);
        float du = delta_t * u;
        const float* bcr = bc + tt * 32;
        if (!FINAL) cumd += delta_t;
        float ys = 0.0f;
#pragma unroll
        for (int jj = 0; jj < 4; ++jj) {
            float4 Bv = *(const float4*)(bcr + jj * 4);
            float4 Cv;
            if (FINAL) Cv = *(const float4*)(bcr + 16 + jj * 4);
#pragma unroll
            for (int j = 0; j < 4; ++j) {
                int s = jj * 4 + j;
                float dA = fexp2_(delta_t * aa[s]);
                hs[s] = fmaf(dA, hs[s], du * ((const float*)&Bv)[j]);
                if (FINAL) ys = fmaf(hs[s], ((const float*)&Cv)[j], ys);
            }
        }
        if (FINAL) {
            float yv = fmaf(u, Dpd, ys);
            yv = fmaf(0.7f, yv, 0.3f * u);
            yC[(size_t)tt * 256] = (__bf16)yv;
        }
    }
    if (!FINAL) {
#pragma unroll
        for (int jj = 0; jj < 4; ++jj) {
            float4 pv, sv;
            pv.x = fexp2_(aa[jj * 4 + 0] * cumd);
            pv.y = fexp2_(aa[jj * 4 + 1] * cumd);
            pv.z = fexp2_(aa[jj * 4 + 2] * cumd);
            pv.w = fexp2_(aa[jj * 4 + 3] * cumd);
            sv.x = hs[jj * 4 + 0]; sv.y = hs[jj * 4 + 1];
            sv.z = hs[jj * 4 + 2]; sv.w = hs[jj * 4 + 3];
            *(float4*)(P + psIdx + jj * 4) = pv;
            *(float4*)(S + psIdx + jj * 4) = sv;
        }
    }
}

// ---------------- mean-pool over L: deterministic two-stage ----------------------
__global__ __launch_bounds__(128) void k_pool(const float* __restrict__ h,
        float* __restrict__ partial) {
    int b = blockIdx.x, lc = blockIdx.y;
    int m = threadIdx.x;
    const float* hb = h + (size_t)b * 131072 + (size_t)lc * 128 * 128 + m;
    float acc = 0.0f;
#pragma unroll 8
    for (int l = 0; l < 128; ++l) acc += hb[(size_t)l * 128];
    partial[((size_t)b * 8 + lc) * 128 + m] = acc;
}

// ---------------- final LN + classifier (sums 8 partials) ------------------------
__global__ __launch_bounds__(128) void k_head(const float* __restrict__ partial,
        const float* __restrict__ nw, const float* __restrict__ nb,
        const float* __restrict__ cw, const float* __restrict__ cb,
        float* __restrict__ out) {
    __shared__ float zs[128];
    __shared__ float red[128];
    int b = blockIdx.x, m = threadIdx.x;
    float v = 0.0f;
#pragma unroll
    for (int lc = 0; lc < 8; ++lc) v += partial[((size_t)b * 8 + lc) * 128 + m];
    v *= (1.0f / 1024.0f);
    red[m] = v;
    __syncthreads();
    for (int off = 64; off; off >>= 1) {
        if (m < off) red[m] += red[m + off];
        __syncthreads();
    }
    float mean = red[0] * (1.0f / 128.0f);
    __syncthreads();
    float dv = v - mean;
    red[m] = dv * dv;
    __syncthreads();
    for (int off = 64; off; off >>= 1) {
        if (m < off) red[m] += red[m + off];
        __syncthreads();
    }
    float rstd = rsqrtf(red[0] * (1.0f / 128.0f) + 1e-5f);
    zs[m] = dv * rstd * nw[m] + nb[m];
    __syncthreads();
    if (m < NC_) {
        float acc = cb[m];
#pragma unroll 8
        for (int k = 0; k < 128; ++k) acc = fmaf(zs[k], cw[k * 10 + m], acc);
        out[b * 10 + m] = acc;
    }
}

extern "C" void kernel_launch(void* const* d_in, const int* in_sizes, int n_in,
                              void* d_out, int out_size, void* d_ws, size_t ws_size,
                              hipStream_t stream) {
    const float* x    = (const float*)d_in[0];
    const float* Win  = (const float*)d_in[1];
    const float* bin  = (const float*)d_in[2];
    const float* lnw  = (const float*)d_in[3];
    const float* lnb  = (const float*)d_in[4];
    const float* ipw  = (const float*)d_in[5];
    const float* cw   = (const float*)d_in[6];
    const float* cb   = (const float*)d_in[7];
    const float* xpw  = (const float*)d_in[8];
    const float* dtw  = (const float*)d_in[9];
    const float* dtb  = (const float*)d_in[10];
    const float* Alog = (const float*)d_in[11];
    const float* Dp   = (const float*)d_in[12];
    const float* opw  = (const float*)d_in[13];
    const float* opb  = (const float*)d_in[14];
    const float* nw   = (const float*)d_in[15];
    const float* nb   = (const float*)d_in[16];
    const float* clw  = (const float*)d_in[17];
    const float* clb  = (const float*)d_in[18];

    // f32-slot offsets (all non-overlapping):
    //   h        [0,        4194304)
    //   P        [4194304,  6291456)   (zb bf16 aliases P; P/S live only
    //   Sb       [6291456,  8388608)    between scanA..scanC of one layer)
    //   xzb bf16 [8388608,  16777216)
    //   xcb bf16 [16777216, 20971520)
    //   projall  [20971520, 25690112)
    //   yb bf16  [25690112, 29884416)
    //   partial  [29884416, 29917184)
    //   wt1      [29917184, 30048256)
    //   wt2      [30048256, 30113792)
    //   wcat     [30113792, 30310400)
    float* ws = (float*)d_ws;
    float*  h       = ws;
    float*  P       = ws + 4194304;
    float*  Sb      = ws + 6291456;
    __bf16* zb      = (__bf16*)P;
    __bf16* xzb     = (__bf16*)(ws + 8388608);
    __bf16* xcb     = (__bf16*)(ws + 16777216);
    __bf16* projall = (__bf16*)(ws + 20971520);
    __bf16* yb      = (__bf16*)(ws + 25690112);
    float*  partial = ws + 29884416;
    __bf16* wt1     = (__bf16*)(ws + 29917184);
    __bf16* wt2     = (__bf16*)(ws + 30048256);
    __bf16* wcat    = (__bf16*)(ws + 30113792);

    k_prep<<<1536, 256, 0, stream>>>(ipw, opw, xpw, dtw, wt1, wt2, wcat);
    k_embed<<<T_, 128, 0, stream>>>(x, Win, bin, h);
    k_ln<<<T_ / 4, 256, 0, stream>>>(h, lnw, lnb, zb);   // layer-0 LN only
    for (int lay = 0; lay < 4; ++lay) {
        k_gemm_mfma<64, 128, 512, 0, false, false><<<dim3(T_ / 64, 4), 256, 0, stream>>>(
            zb, nullptr, wt1 + (size_t)lay * 65536, nullptr, nullptr, xzb,
            nullptr, nullptr, nullptr);
        k_conv<<<T_ / 4, 256, 0, stream>>>(xzb, cw + lay * 1024, cb + lay * 256, xcb);
        k_gemm_mfma<64, 256, 384, 1, false, false><<<dim3(T_ / 64, 3), 256, 0, stream>>>(
            xcb, nullptr, wcat + (size_t)lay * 98304, dtb + lay * 256, nullptr, projall,
            nullptr, nullptr, nullptr);
        k_scan_chunk<false><<<dim3(2, NCH_, B_), 128, 0, stream>>>(projall, xcb,
            Alog + lay * 4096, Dp + lay * 256, P, Sb, yb);
        k_scan_chunk<true><<<dim3(2, NCH_, B_), 128, 0, stream>>>(projall, xcb,
            Alog + lay * 4096, Dp + lay * 256, P, Sb, yb);
        if (lay < 3) {
            k_gemm_mfma<32, 256, 128, 2, true, true><<<dim3(T_ / 32, 1), 256, 0, stream>>>(
                yb, xzb, wt2 + (size_t)lay * 32768, opb + lay * 128, h, nullptr,
                lnw + (lay + 1) * 128, lnb + (lay + 1) * 128, zb);
        } else {
            k_gemm_mfma<32, 256, 128, 2, true, false><<<dim3(T_ / 32, 1), 256, 0, stream>>>(
                yb, xzb, wt2 + (size_t)lay * 32768, opb + lay * 128, h, nullptr,
                nullptr, nullptr, nullptr);
        }
    }
    k_pool<<<dim3(32, 8), 128, 0, stream>>>(h, partial);
    k_head<<<32, 128, 0, stream>>>(partial, nw, nb, clw, clb, (float*)d_out);
}

// Round 13
// 617.202 us; speedup vs baseline: 1.0414x; 1.0414x over previous
//
#include <hip/hip_runtime.h>
#include <math.h>

// Problem constants
#define B_  32
#define L_  1024
#define T_  (B_ * L_)       // 32768 tokens
#define DM_ 128
#define DI_ 256
#define DS_ 16
#define DC_ 4
#define DR_ 8
#define NC_ 10
#define CHUNK_ 32
#define NCH_  (L_ / CHUNK_)   // 32 chunks
#define PSTR_ 288             // projall row stride (bf16): 256 delta | 32 B,C

typedef __bf16 bf16x8 __attribute__((ext_vector_type(8)));
typedef __bf16 bf16x4 __attribute__((ext_vector_type(4)));
typedef __bf16 bf16x2 __attribute__((ext_vector_type(2)));
typedef float f32x4 __attribute__((ext_vector_type(4)));
typedef unsigned short u16x8 __attribute__((ext_vector_type(8)));

__device__ __forceinline__ float sigmoidf_(float x) { return 1.0f / (1.0f + __expf(-x)); }
__device__ __forceinline__ float siluf_(float x)    { return x * sigmoidf_(x); }
__device__ __forceinline__ float softplusf_(float x) {
    return (x > 15.0f) ? x : __logf(1.0f + __expf(x));
}
__device__ __forceinline__ float fexp2_(float x) { return __builtin_amdgcn_exp2f(x); }

// async 16B global->LDS (gfx950). dest = wave-uniform base + lane*16.
__device__ __forceinline__ void gload_lds16(const __bf16* g, __bf16* l) {
    __builtin_amdgcn_global_load_lds(
        (const __attribute__((address_space(1))) void*)g,
        (__attribute__((address_space(3))) void*)l, 16, 0, 0);
}

// Stage an R x 64 bf16 tile (row stride `stride`, col offset k0) into LDS with
// XOR-swizzle baked in: LDS (row, sw) holds source (row, sw ^ (row&7)).
template<int R>
__device__ __forceinline__ void stage_async(const __bf16* __restrict__ src,
        __bf16* lds, int k0, int stride, int wid, int lane) {
    constexpr int NI = R / 32;
#pragma unroll
    for (int j = 0; j < NI; ++j) {
        int s0 = (wid * NI + j) * 64;
        int s = s0 + lane;
        int row = s >> 3, sw = s & 7;
        int slot = sw ^ (row & 7);
        gload_lds16(src + (size_t)row * stride + k0 + slot * 8, lds + (size_t)s0 * 8);
    }
}

// ---------------- embed -----------------------------------------------------------
__global__ __launch_bounds__(128) void k_embed(const float* __restrict__ x,
        const float* __restrict__ Win, const float* __restrict__ bin,
        float* __restrict__ h) {
    int t = blockIdx.x;
    int b = t >> 10, l = t & 1023;
    int m = threadIdx.x;
    const float* xb = x + (size_t)b * 3 * 1024 + l;
    float acc = bin[m];
    acc = fmaf(xb[0],    Win[m],        acc);
    acc = fmaf(xb[1024], Win[128 + m],  acc);
    acc = fmaf(xb[2048], Win[256 + m],  acc);
    h[(size_t)t * 128 + m] = acc;
}

// ---------------- merged weight prep ----------------------------------------------
__global__ __launch_bounds__(256) void k_prep(const float* __restrict__ ipw,
        const float* __restrict__ opw, const float* __restrict__ xpw,
        const float* __restrict__ dtw, __bf16* __restrict__ wt1,
        __bf16* __restrict__ wt2, __bf16* __restrict__ wcat) {
    int blk = blockIdx.x;              // 0..1535
    int tid = threadIdx.x;
    int i = blk * 256 + tid;
    if (i < 262144) {
        int lay = i >> 16, rem = i & 65535, n = rem >> 7, k = rem & 127;
        wt1[i] = (__bf16)ipw[lay * 65536 + k * 512 + n];
    }
    if (i < 131072) {
        int lay = i >> 15, rem = i & 32767, n = rem >> 8, k = rem & 255;
        wt2[i] = (__bf16)opw[lay * 32768 + k * 128 + n];
    }
    {
        int lay = blk / 384, n = blk % 384;
        int k = tid;
        float v;
        if (n < 256) {
            float acc = 0.0f;
#pragma unroll
            for (int r = 0; r < 8; ++r)
                acc = fmaf(xpw[lay * 10240 + k * 40 + r], dtw[lay * 2048 + r * 256 + n], acc);
            v = acc;
        } else if (n < 288) {
            v = xpw[lay * 10240 + k * 40 + (n - 248)];   // col 8 + (n-256)
        } else {
            v = 0.0f;
        }
        wcat[(size_t)blk * 256 + k] = (__bf16)v;
    }
}

// ---------------- layernorm -> bf16 (layer 0 only) --------------------------------
__global__ __launch_bounds__(256) void k_ln(const float* __restrict__ h,
        const float* __restrict__ w, const float* __restrict__ b,
        __bf16* __restrict__ z) {
    int wid = threadIdx.x >> 6, lane = threadIdx.x & 63;
    int t = blockIdx.x * 4 + wid;
    const float* hr = h + (size_t)t * 128;
    float2 v = *(const float2*)(hr + lane * 2);
    float s = v.x + v.y, sq = v.x * v.x + v.y * v.y;
#pragma unroll
    for (int off = 1; off < 64; off <<= 1) {
        s += __shfl_xor(s, off);
        sq += __shfl_xor(sq, off);
    }
    float mean = s * (1.0f / 128.0f);
    float var = sq * (1.0f / 128.0f) - mean * mean;
    float rstd = rsqrtf(var + 1e-5f);
    float2 wv = *(const float2*)(w + lane * 2);
    float2 bv = *(const float2*)(b + lane * 2);
    bf16x2 o;
    o.x = (__bf16)((v.x - mean) * rstd * wv.x + bv.x);
    o.y = (__bf16)((v.y - mean) * rstd * wv.y + bv.y);
    *(bf16x2*)(z + (size_t)t * 128 + lane * 2) = o;
}

// ---------------- bf16 MFMA GEMM, BM x 128 tile, BK=64 ---------------------------
// MODE 0: store bf16 (stride N)              [gemm1 -> xzb]
// MODE 1: col<256 softplus+bias bf16, col<288 raw bf16; stride PSTR_  [xproj]
// MODE 2: Cf += acc + bias (f32, stride N)   [gemm2 -> h]
// GATE: A element = f32(A[m][k]) * silu(f32(G[m*512+256+k]))
// WLN (MODE 2, N=128): fused row-LayerNorm writing next layer's zb.
template<int BM, int K, int N, int MODE, bool GATE, bool WLN>
__global__ __launch_bounds__(256) void k_gemm_mfma(
        const __bf16* __restrict__ A, const __bf16* __restrict__ G,
        const __bf16* __restrict__ Wt, const float* __restrict__ bias,
        float* __restrict__ Cf, __bf16* __restrict__ Cb,
        const float* __restrict__ lnw, const float* __restrict__ lnb,
        __bf16* __restrict__ Zb) {
    static_assert(!GATE || BM == 32, "GATE staging assumes BM=32");
    static_assert(!WLN || (MODE == 2 && BM == 32 && N == 128), "WLN geometry");
    __shared__ __bf16 As[BM * 64];
    __shared__ __bf16 Bs[128 * 64];
    __shared__ float red_s[WLN ? 4 : 1][WLN ? 32 : 1];
    __shared__ float red_q[WLN ? 4 : 1][WLN ? 32 : 1];
    int tid = threadIdx.x;
    int bm = blockIdx.x, bn = blockIdx.y;
    int lane = tid & 63, wid = tid >> 6;
    int lr = lane & 15, lg = lane >> 4;
    constexpr int MF = BM / 16;

    f32x4 acc[MF][2] = {};
    const __bf16* Asrc = A + (size_t)(bm * BM) * K;
    const __bf16* Bsrc = Wt + (size_t)(bn * 128) * K;

    for (int k0 = 0; k0 < K; k0 += 64) {
        if (GATE) {
            int row = tid >> 3, slot = tid & 7;
            int m = bm * BM + row;
            bf16x8 yv = *(const bf16x8*)(A + (size_t)m * K + k0 + slot * 8);
            bf16x8 gv = *(const bf16x8*)(G + (size_t)m * 512 + 256 + k0 + slot * 8);
            bf16x8 v;
#pragma unroll
            for (int j = 0; j < 8; ++j)
                v[j] = (__bf16)((float)yv[j] * siluf_((float)gv[j]));
            *(bf16x8*)(As + row * 64 + ((slot ^ (row & 7)) * 8)) = v;
        } else {
            stage_async<BM>(Asrc, As, k0, K, wid, lane);
        }
        stage_async<128>(Bsrc, Bs, k0, K, wid, lane);
        __syncthreads();
#pragma unroll
        for (int ks = 0; ks < 2; ++ks) {
            int slotbase = ks * 4 + lg;
            bf16x8 af[MF], bfr[2];
#pragma unroll
            for (int m = 0; m < MF; ++m) {
                int row = m * 16 + lr;
                af[m] = *(const bf16x8*)(As + row * 64 + ((slotbase ^ (row & 7)) * 8));
            }
#pragma unroll
            for (int n = 0; n < 2; ++n) {
                int rn = wid * 32 + n * 16 + lr;
                bfr[n] = *(const bf16x8*)(Bs + rn * 64 + ((slotbase ^ (rn & 7)) * 8));
            }
#pragma unroll
            for (int m = 0; m < MF; ++m)
#pragma unroll
                for (int n = 0; n < 2; ++n)
                    acc[m][n] = __builtin_amdgcn_mfma_f32_16x16x32_bf16(
                        af[m], bfr[n], acc[m][n], 0, 0, 0);
        }
        __syncthreads();
    }
    // ---- epilogue: D[row=(lane>>4)*4+reg][col=lane&15] ----
    float vv[MF][2][4];
#pragma unroll
    for (int m = 0; m < MF; ++m) {
#pragma unroll
        for (int n = 0; n < 2; ++n) {
            int col = bn * 128 + wid * 32 + n * 16 + lr;
            float bv = (MODE == 2) ? bias[col] : 0.0f;
            float dtbv = (MODE == 1 && col < 256) ? bias[col] : 0.0f;
#pragma unroll
            for (int rg = 0; rg < 4; ++rg) {
                int row = bm * BM + m * 16 + lg * 4 + rg;
                float v = acc[m][n][rg];
                if (MODE == 0) {
                    Cb[(size_t)row * N + col] = (__bf16)v;
                } else if (MODE == 1) {
                    if (col < 256)
                        Cb[(size_t)row * PSTR_ + col] = (__bf16)softplusf_(v + dtbv);
                    else if (col < 288)
                        Cb[(size_t)row * PSTR_ + col] = (__bf16)v;
                } else {
                    float* cp = Cf + (size_t)row * N + col;
                    v += *cp + bv;
                    *cp = v;
                    vv[m][n][rg] = v;
                }
            }
        }
    }
    if (WLN) {
        float ps[MF][4], pq[MF][4];
#pragma unroll
        for (int m = 0; m < MF; ++m)
#pragma unroll
            for (int rg = 0; rg < 4; ++rg) {
                float a = vv[m][0][rg], bv2 = vv[m][1][rg];
                ps[m][rg] = a + bv2;
                pq[m][rg] = a * a + bv2 * bv2;
            }
#pragma unroll
        for (int off = 1; off < 16; off <<= 1) {
#pragma unroll
            for (int m = 0; m < MF; ++m)
#pragma unroll
                for (int rg = 0; rg < 4; ++rg) {
                    ps[m][rg] += __shfl_xor(ps[m][rg], off);
                    pq[m][rg] += __shfl_xor(pq[m][rg], off);
                }
        }
        if (lr == 0) {
#pragma unroll
            for (int m = 0; m < MF; ++m)
#pragma unroll
                for (int rg = 0; rg < 4; ++rg) {
                    int rl = m * 16 + lg * 4 + rg;
                    red_s[wid][rl] = ps[m][rg];
                    red_q[wid][rl] = pq[m][rg];
                }
        }
        __syncthreads();
#pragma unroll
        for (int m = 0; m < MF; ++m)
#pragma unroll
            for (int rg = 0; rg < 4; ++rg) {
                int rl = m * 16 + lg * 4 + rg;
                float s = red_s[0][rl] + red_s[1][rl] + red_s[2][rl] + red_s[3][rl];
                float q = red_q[0][rl] + red_q[1][rl] + red_q[2][rl] + red_q[3][rl];
                float mean = s * (1.0f / 128.0f);
                float var = q * (1.0f / 128.0f) - mean * mean;
                float rstd = rsqrtf(var + 1e-5f);
#pragma unroll
                for (int n = 0; n < 2; ++n) {
                    int col = wid * 32 + n * 16 + lr;
                    float z = (vv[m][n][rg] - mean) * rstd * lnw[col] + lnb[col];
                    Zb[(size_t)(bm * BM + rl) * 128 + col] = (__bf16)z;
                }
            }
    }
}

// ---------------- causal depthwise conv (width 4) + SiLU, vectorized -------------
__global__ __launch_bounds__(256) void k_conv(const __bf16* __restrict__ xzb,
        const float* __restrict__ cw, const float* __restrict__ cb,
        __bf16* __restrict__ xcb) {
    int t = blockIdx.x * 4 + (threadIdx.x >> 6);
    int d0 = (threadIdx.x & 63) * 4;
    int l = t & 1023;
    const __bf16* xp = xzb + (size_t)t * 512 + d0;
    float4 wv[4];
#pragma unroll
    for (int j = 0; j < 4; ++j) wv[j] = *(const float4*)(cw + (d0 + j) * 4);
    float acc[4] = {cb[d0], cb[d0 + 1], cb[d0 + 2], cb[d0 + 3]};
#pragma unroll
    for (int k = 0; k < 4; ++k) {
        int back = 3 - k;
        if (l >= back) {
            bf16x4 v = *(const bf16x4*)(xp - back * 512);
#pragma unroll
            for (int j = 0; j < 4; ++j)
                acc[j] = fmaf((float)v[j], ((const float*)&wv[j])[k], acc[j]);
        }
    }
    bf16x4 o;
#pragma unroll
    for (int j = 0; j < 4; ++j) o[j] = (__bf16)siluf_(acc[j]);
    *(bf16x4*)(xcb + (size_t)t * 256 + d0) = o;
}

// ---------------- chunk-parallel SSM scan: one thread per d ----------------------
// CHUNK_=32 -> grid (2, 32, 32) = 2048 blocks, 128 threads, 20 KB LDS.
template<bool FINAL>
__global__ __launch_bounds__(128) void k_scan_chunk(
        const __bf16* __restrict__ projall, const __bf16* __restrict__ xcb,
        const float* __restrict__ Alog, const float* __restrict__ Dp,
        float* __restrict__ P, float* __restrict__ S,
        __bf16* __restrict__ yb) {
    __shared__ unsigned du_lds[CHUNK_ * 128];   // 16 KB
    __shared__ float bc[CHUNK_ * 32];           // 4 KB
    int b = blockIdx.z, c = blockIdx.y, dg = blockIdx.x;   // dg in {0,1}
    int tid = threadIdx.x;                      // 0..127
    int d = dg * 128 + tid;

    const __bf16* projC = projall + ((size_t)b * 1024 + c * CHUNK_) * PSTR_;
    const __bf16* xcC   = xcb + ((size_t)b * 1024 + c * CHUNK_) * 256 + dg * 128;

    // ---- stage delta|u interleaved: CHUNK_*16 granules of 8 d's ----
#pragma unroll
    for (int r = 0; r < (CHUNK_ * 16) / 128; ++r) {
        int item = r * 128 + tid;
        int t = item >> 4, o8 = (item & 15) * 8;
        u16x8 dv = *(const u16x8*)(projC + (size_t)t * PSTR_ + dg * 128 + o8);
        u16x8 xv = *(const u16x8*)(xcC + (size_t)t * 256 + o8);
        uint4 w0, w1;
        w0.x = dv[0] | ((unsigned)xv[0] << 16); w0.y = dv[1] | ((unsigned)xv[1] << 16);
        w0.z = dv[2] | ((unsigned)xv[2] << 16); w0.w = dv[3] | ((unsigned)xv[3] << 16);
        w1.x = dv[4] | ((unsigned)xv[4] << 16); w1.y = dv[5] | ((unsigned)xv[5] << 16);
        w1.z = dv[6] | ((unsigned)xv[6] << 16); w1.w = dv[7] | ((unsigned)xv[7] << 16);
        *(uint4*)(du_lds + t * 128 + o8)     = w0;
        *(uint4*)(du_lds + t * 128 + o8 + 4) = w1;
    }
    // ---- stage B|C as f32: CHUNK_*4 granules of 8 ----
#pragma unroll
    for (int r = 0; r < (CHUNK_ * 4) / 128; ++r) {
        int item = r * 128 + tid;
        int t = item >> 2, g8 = (item & 3) * 8;
        bf16x8 v = *(const bf16x8*)(projC + (size_t)t * PSTR_ + 256 + g8);
        float4 f0 = {(float)v[0], (float)v[1], (float)v[2], (float)v[3]};
        float4 f1 = {(float)v[4], (float)v[5], (float)v[6], (float)v[7]};
        *(float4*)(bc + t * 32 + g8)     = f0;
        *(float4*)(bc + t * 32 + g8 + 4) = f1;
    }

    // ---- per-thread constants: all 16 states ----
    float aa[16], hs[16];
#pragma unroll
    for (int jj = 0; jj < 4; ++jj) {
        float4 av = *(const float4*)(Alog + (size_t)d * 16 + jj * 4);
        aa[jj * 4 + 0] = -__expf(av.x) * 1.44269504088896f;
        aa[jj * 4 + 1] = -__expf(av.y) * 1.44269504088896f;
        aa[jj * 4 + 2] = -__expf(av.z) * 1.44269504088896f;
        aa[jj * 4 + 3] = -__expf(av.w) * 1.44269504088896f;
    }
    float Dpd = Dp[d];
    size_t psIdx = ((size_t)(b * NCH_ + c)) * 4096 + (size_t)d * 16;
    if (FINAL) {
#pragma unroll
        for (int jj = 0; jj < 4; ++jj) {
            float4 h0 = *(const float4*)(P + psIdx + jj * 4);
            hs[jj * 4 + 0] = h0.x; hs[jj * 4 + 1] = h0.y;
            hs[jj * 4 + 2] = h0.z; hs[jj * 4 + 3] = h0.w;
        }
    } else {
#pragma unroll
        for (int j = 0; j < 16; ++j) hs[j] = 0.0f;
    }
    float cumd = 0.0f;
    __bf16* yC = yb + ((size_t)b * 1024 + c * CHUNK_) * 256 + dg * 128 + tid;

    __syncthreads();
#pragma unroll 2
    for (int tt = 0; tt < CHUNK_; ++tt) {
        unsigned duv = du_lds[tt * 128 + tid];
        float delta_t = __uint_as_float(duv << 16);
        float u = __uint_as_float(duv & 0xffff0000u);
        float du = delta_t * u;
        const float* bcr = bc + tt * 32;
        if (!FINAL) cumd += delta_t;
        float ys = 0.0f;
#pragma unroll
        for (int jj = 0; jj < 4; ++jj) {
            float4 Bv = *(const float4*)(bcr + jj * 4);
            float4 Cv;
            if (FINAL) Cv = *(const float4*)(bcr + 16 + jj * 4);
#pragma unroll
            for (int j = 0; j < 4; ++j) {
                int s = jj * 4 + j;
                float dA = fexp2_(delta_t * aa[s]);
                hs[s] = fmaf(dA, hs[s], du * ((const float*)&Bv)[j]);
                if (FINAL) ys = fmaf(hs[s], ((const float*)&Cv)[j], ys);
            }
        }
        if (FINAL) {
            float yv = fmaf(u, Dpd, ys);
            yv = fmaf(0.7f, yv, 0.3f * u);
            yC[(size_t)tt * 256] = (__bf16)yv;
        }
    }
    if (!FINAL) {
#pragma unroll
        for (int jj = 0; jj < 4; ++jj) {
            float4 pv, sv;
            pv.x = fexp2_(aa[jj * 4 + 0] * cumd);
            pv.y = fexp2_(aa[jj * 4 + 1] * cumd);
            pv.z = fexp2_(aa[jj * 4 + 2] * cumd);
            pv.w = fexp2_(aa[jj * 4 + 3] * cumd);
            sv.x = hs[jj * 4 + 0]; sv.y = hs[jj * 4 + 1];
            sv.z = hs[jj * 4 + 2]; sv.w = hs[jj * 4 + 3];
            *(float4*)(P + psIdx + jj * 4) = pv;
            *(float4*)(S + psIdx + jj * 4) = sv;
        }
    }
}

// ---------------- combine chunk aggregates: H_{c+1} = P_c*H_c + S_c --------------
// One thread per (b,d,s) = 131072 threads; overwrites P[c] with chunk-start H.
__global__ __launch_bounds__(256) void k_scan_combine(float* __restrict__ P,
        const float* __restrict__ S) {
    int idx = blockIdx.x * 256 + threadIdx.x;
    int b = idx >> 12, rem = idx & 4095;
    float h = 0.0f;
#pragma unroll
    for (int c = 0; c < NCH_; ++c) {
        size_t base = ((size_t)(b * NCH_ + c)) * 4096 + rem;
        float p = P[base];
        float s = S[base];
        P[base] = h;
        h = fmaf(p, h, s);
    }
}

// ---------------- mean-pool over L: deterministic two-stage ----------------------
__global__ __launch_bounds__(128) void k_pool(const float* __restrict__ h,
        float* __restrict__ partial) {
    int b = blockIdx.x, lc = blockIdx.y;
    int m = threadIdx.x;
    const float* hb = h + (size_t)b * 131072 + (size_t)lc * 128 * 128 + m;
    float acc = 0.0f;
#pragma unroll 8
    for (int l = 0; l < 128; ++l) acc += hb[(size_t)l * 128];
    partial[((size_t)b * 8 + lc) * 128 + m] = acc;
}

// ---------------- final LN + classifier (sums 8 partials) ------------------------
__global__ __launch_bounds__(128) void k_head(const float* __restrict__ partial,
        const float* __restrict__ nw, const float* __restrict__ nb,
        const float* __restrict__ cw, const float* __restrict__ cb,
        float* __restrict__ out) {
    __shared__ float zs[128];
    __shared__ float red[128];
    int b = blockIdx.x, m = threadIdx.x;
    float v = 0.0f;
#pragma unroll
    for (int lc = 0; lc < 8; ++lc) v += partial[((size_t)b * 8 + lc) * 128 + m];
    v *= (1.0f / 1024.0f);
    red[m] = v;
    __syncthreads();
    for (int off = 64; off; off >>= 1) {
        if (m < off) red[m] += red[m + off];
        __syncthreads();
    }
    float mean = red[0] * (1.0f / 128.0f);
    __syncthreads();
    float dv = v - mean;
    red[m] = dv * dv;
    __syncthreads();
    for (int off = 64; off; off >>= 1) {
        if (m < off) red[m] += red[m + off];
        __syncthreads();
    }
    float rstd = rsqrtf(red[0] * (1.0f / 128.0f) + 1e-5f);
    zs[m] = dv * rstd * nw[m] + nb[m];
    __syncthreads();
    if (m < NC_) {
        float acc = cb[m];
#pragma unroll 8
        for (int k = 0; k < 128; ++k) acc = fmaf(zs[k], cw[k * 10 + m], acc);
        out[b * 10 + m] = acc;
    }
}

extern "C" void kernel_launch(void* const* d_in, const int* in_sizes, int n_in,
                              void* d_out, int out_size, void* d_ws, size_t ws_size,
                              hipStream_t stream) {
    const float* x    = (const float*)d_in[0];
    const float* Win  = (const float*)d_in[1];
    const float* bin  = (const float*)d_in[2];
    const float* lnw  = (const float*)d_in[3];
    const float* lnb  = (const float*)d_in[4];
    const float* ipw  = (const float*)d_in[5];
    const float* cw   = (const float*)d_in[6];
    const float* cb   = (const float*)d_in[7];
    const float* xpw  = (const float*)d_in[8];
    const float* dtw  = (const float*)d_in[9];
    const float* dtb  = (const float*)d_in[10];
    const float* Alog = (const float*)d_in[11];
    const float* Dp   = (const float*)d_in[12];
    const float* opw  = (const float*)d_in[13];
    const float* opb  = (const float*)d_in[14];
    const float* nw   = (const float*)d_in[15];
    const float* nb   = (const float*)d_in[16];
    const float* clw  = (const float*)d_in[17];
    const float* clb  = (const float*)d_in[18];

    // f32-slot offsets (all non-overlapping in time):
    //   h        [0,        4194304)
    //   P        [4194304,  8388608)   B*NCH*4096 = 4,194,304 f32 (NCH=32).
    //            zb bf16 aliases [4194304, 6291456): zb is consumed by gemm1
    //            before scanA writes P; zb rewritten by gemm2 after scanC.
    //   xzb bf16 [8388608,  16777216)
    //   xcb bf16 [16777216, 20971520)
    //   projall  [20971520, 25690112)
    //   yb bf16  [25690112, 29884416)
    //   partial  [29884416, 29917184)
    //   wt1      [29917184, 30048256)
    //   wt2      [30048256, 30113792)
    //   wcat     [30113792, 30310400)
    //   Sb       [30310400, 34504704)  4,194,304 f32
    float* ws = (float*)d_ws;
    float*  h       = ws;
    float*  P       = ws + 4194304;
    __bf16* zb      = (__bf16*)(ws + 4194304);
    __bf16* xzb     = (__bf16*)(ws + 8388608);
    __bf16* xcb     = (__bf16*)(ws + 16777216);
    __bf16* projall = (__bf16*)(ws + 20971520);
    __bf16* yb      = (__bf16*)(ws + 25690112);
    float*  partial = ws + 29884416;
    __bf16* wt1     = (__bf16*)(ws + 29917184);
    __bf16* wt2     = (__bf16*)(ws + 30048256);
    __bf16* wcat    = (__bf16*)(ws + 30113792);
    float*  Sb      = ws + 30310400;

    k_prep<<<1536, 256, 0, stream>>>(ipw, opw, xpw, dtw, wt1, wt2, wcat);
    k_embed<<<T_, 128, 0, stream>>>(x, Win, bin, h);
    k_ln<<<T_ / 4, 256, 0, stream>>>(h, lnw, lnb, zb);   // layer-0 LN only
    for (int lay = 0; lay < 4; ++lay) {
        k_gemm_mfma<64, 128, 512, 0, false, false><<<dim3(T_ / 64, 4), 256, 0, stream>>>(
            zb, nullptr, wt1 + (size_t)lay * 65536, nullptr, nullptr, xzb,
            nullptr, nullptr, nullptr);
        k_conv<<<T_ / 4, 256, 0, stream>>>(xzb, cw + lay * 1024, cb + lay * 256, xcb);
        k_gemm_mfma<64, 256, 384, 1, false, false><<<dim3(T_ / 64, 3), 256, 0, stream>>>(
            xcb, nullptr, wcat + (size_t)lay * 98304, dtb + lay * 256, nullptr, projall,
            nullptr, nullptr, nullptr);
        k_scan_chunk<false><<<dim3(2, NCH_, B_), 128, 0, stream>>>(projall, xcb,
            Alog + lay * 4096, Dp + lay * 256, P, Sb, yb);
        k_scan_combine<<<B_ * 4096 / 256, 256, 0, stream>>>(P, Sb);
        k_scan_chunk<true><<<dim3(2, NCH_, B_), 128, 0, stream>>>(projall, xcb,
            Alog + lay * 4096, Dp + lay * 256, P, Sb, yb);
        if (lay < 3) {
            k_gemm_mfma<32, 256, 128, 2, true, true><<<dim3(T_ / 32, 1), 256, 0, stream>>>(
                yb, xzb, wt2 + (size_t)lay * 32768, opb + lay * 128, h, nullptr,
                lnw + (lay + 1) * 128, lnb + (lay + 1) * 128, zb);
        } else {
            k_gemm_mfma<32, 256, 128, 2, true, false><<<dim3(T_ / 32, 1), 256, 0, stream>>>(
                yb, xzb, wt2 + (size_t)lay * 32768, opb + lay * 128, h, nullptr,
                nullptr, nullptr, nullptr);
        }
    }
    k_pool<<<dim3(32, 8), 128, 0, stream>>>(h, partial);
    k_head<<<32, 128, 0, stream>>>(partial, nw, nb, clw, clb, (float*)d_out);
}